// Round 5
// baseline (229.578 us; speedup 1.0000x reference)
//
#include <hip/hip_runtime.h>

// AlgebraicAttention on MI355X (gfx950), round 5.
// R4 post-mortem: attn 58us, conflicts 6.4M, Occ 22% -> per-chunk latency bound:
// V-transpose scatter writes + Ws A-frag reads at row-stride 64 (16-way bank conflict).
// Fixes: (1) V^T produced directly by GEMM (V^T = Wv @ x^T, same A@B^T kernel shape),
// attention stages V via global_load_lds; (2) Ws padded to stride 68 (conflict-free
// writes, <=4-way reads as 2x b64).
// ws layout (>=24MB proven):
//   ws[0,8M)   xb (QKV input); dead after -> Opart [1024][64][64] bf16
//   ws[8,10M)  wqb; dead after QKV -> Dpart [1024][64] f32
//   ws[10,12M) wkb  ws[12,14M) wvb (dead after QKV)   ws[14,16M) wob (live to end)
//   ws[16,24M) Qb [4096][1024]; attention output in-place
//   d_out[0,8M) Kb [4096][1024]   d_out[8,16M) Vtg [1024][4096] (V^T)

typedef __attribute__((ext_vector_type(8))) __bf16 bf16x8;
typedef __attribute__((ext_vector_type(4))) __bf16 bf16x4;
typedef __attribute__((ext_vector_type(4))) float f32x4;
typedef unsigned short u16;

__device__ __forceinline__ u16 f2bf(float f) {
  unsigned u = __float_as_uint(f);
  u += 0x7FFFu + ((u >> 16) & 1u);   // round-to-nearest-even
  return (u16)(u >> 16);
}
__device__ __forceinline__ float bf2f(u16 b) {
  return __uint_as_float(((unsigned)b) << 16);
}
__device__ __forceinline__ void gl_lds16(const void* g, void* l) {
  __builtin_amdgcn_global_load_lds((__attribute__((address_space(1))) void*)g,
                                   (__attribute__((address_space(3))) void*)l,
                                   16, 0, 0);
}

// ---------------------------------------------------------------- cast kernel
__global__ __launch_bounds__(256) void cast_all_kernel(
    const float* __restrict__ x,  const float* __restrict__ wq,
    const float* __restrict__ wk, const float* __restrict__ wv,
    const float* __restrict__ wo,
    u16* __restrict__ xb, u16* __restrict__ wqb, u16* __restrict__ wkb,
    u16* __restrict__ wvb, u16* __restrict__ wob) {
  long i4 = (long)blockIdx.x * 256 + threadIdx.x;   // float4 index, < 2097152
  const float* src; u16* dst; long rel;
  if (i4 < 1048576) { src = x; dst = xb; rel = i4; }
  else {
    long j = i4 - 1048576;
    int w = (int)(j >> 18);
    rel = j & 262143;
    src = (w == 0) ? wq : (w == 1) ? wk : (w == 2) ? wv : wo;
    dst = (w == 0) ? wqb : (w == 1) ? wkb : (w == 2) ? wvb : wob;
  }
  float4 v = ((const float4*)src)[rel];
  ushort4 o;
  o.x = f2bf(v.x); o.y = f2bf(v.y); o.z = f2bf(v.z); o.w = f2bf(v.w);
  ((ushort4*)dst)[rel] = o;
}

// ---------------------------------------------------------------- fused QKV + V^T GEMM
// All three are A@B^T with K=1024, m97 staging. bx<512: Q/K (A=x, B=Wq/Wk, col bias,
// C [4096][1024]). bx>=512: V^T = Wv@x^T (A=Wv, B=x, ROW bias, C [1024][4096]).
__global__ __launch_bounds__(256) void gemm_qkv(
    const u16* __restrict__ xb, const u16* __restrict__ wqb,
    const u16* __restrict__ wkb, const u16* __restrict__ wvb,
    const float* __restrict__ bq, const float* __restrict__ bk,
    const float* __restrict__ bv,
    u16* __restrict__ Qb, u16* __restrict__ Kb, u16* __restrict__ Vtg) {
  constexpr int K = 1024;
  __shared__ __align__(16) u16 As[128 * 64];
  __shared__ __align__(16) u16 Bs[128 * 64];

  const int bx = blockIdx.x;
  const u16 *AT, *BT;
  const float* bias;
  u16* C;
  int m0, n0, ldc;
  bool rowbias;
  if (bx < 512) {
    int sel = bx >> 8, rem = bx & 255;
    m0 = (rem >> 3) * 128; n0 = (rem & 7) * 128;
    AT = xb; BT = sel ? wkb : wqb; bias = sel ? bk : bq;
    C = sel ? Kb : Qb; ldc = 1024; rowbias = false;
  } else {
    int rem = bx - 512;
    m0 = (rem >> 5) * 128; n0 = (rem & 31) * 128;
    AT = wvb; BT = xb; bias = bv;
    C = Vtg; ldc = 4096; rowbias = true;
  }

  const int t = threadIdx.x;
  const int lane = t & 63;
  const int wv = t >> 6;
  const int quad = lane >> 4;
  const int l15 = lane & 15;
  const int wr = wv >> 1, wc = wv & 1;

  const f32x4 vzero = {0.f, 0.f, 0.f, 0.f};
  f32x4 acc[4][4];
#pragma unroll
  for (int i = 0; i < 4; ++i)
#pragma unroll
    for (int j = 0; j < 4; ++j) acc[i][j] = vzero;

  for (int kt = 0; kt < K / 64; ++kt) {
    const int k0 = kt * 64;
#pragma unroll
    for (int p = 0; p < 4; ++p) {
      int idx = t + p * 256;
      int row = idx >> 3, seg = idx & 7;
      gl_lds16(&AT[(long)(m0 + row) * K + k0 + seg * 8], &As[idx * 8]);
      gl_lds16(&BT[(long)(n0 + row) * K + k0 + seg * 8], &Bs[idx * 8]);
    }
    __syncthreads();
#pragma unroll
    for (int ks = 0; ks < 64; ks += 32) {
      bf16x8 af[4], bfg[4];
#pragma unroll
      for (int i = 0; i < 4; ++i)
        af[i] = *(const bf16x8*)&As[(wr * 64 + i * 16 + l15) * 64 + ks + quad * 8];
#pragma unroll
      for (int j = 0; j < 4; ++j)
        bfg[j] = *(const bf16x8*)&Bs[(wc * 64 + j * 16 + l15) * 64 + ks + quad * 8];
#pragma unroll
      for (int i = 0; i < 4; ++i)
#pragma unroll
        for (int j = 0; j < 4; ++j)
          acc[i][j] = __builtin_amdgcn_mfma_f32_16x16x32_bf16(af[i], bfg[j], acc[i][j], 0, 0, 0);
    }
    __syncthreads();
  }

  float cb[4];
  if (!rowbias) {
#pragma unroll
    for (int j = 0; j < 4; ++j) cb[j] = bias[n0 + wc * 64 + j * 16 + l15];
  }

#pragma unroll
  for (int i = 0; i < 4; ++i) {
#pragma unroll
    for (int r = 0; r < 4; ++r) {
      int row = m0 + wr * 64 + i * 16 + quad * 4 + r;
      long base = (long)row * ldc + n0 + wc * 64;
      float rb_ = rowbias ? bias[row] : 0.f;
#pragma unroll
      for (int j = 0; j < 4; ++j) {
        float v = acc[i][j][r] + (rowbias ? rb_ : cb[j]);
        C[base + j * 16 + l15] = f2bf(v);
      }
    }
  }
}

// ---------------------------------------------------------------- output GEMM (fp32 out)
__global__ __launch_bounds__(256) void gemm_out(
    const u16* __restrict__ A, const u16* __restrict__ B,
    const float* __restrict__ bias, float* __restrict__ C) {
  constexpr int K = 1024;
  __shared__ __align__(16) u16 As[128 * 64];
  __shared__ __align__(16) u16 Bs[128 * 64];

  const int m0 = blockIdx.x * 128;
  const int n0 = blockIdx.y * 128;

  const int t = threadIdx.x;
  const int lane = t & 63;
  const int wv = t >> 6;
  const int quad = lane >> 4;
  const int l15 = lane & 15;
  const int wr = wv >> 1, wc = wv & 1;

  const f32x4 vzero = {0.f, 0.f, 0.f, 0.f};
  f32x4 acc[4][4];
#pragma unroll
  for (int i = 0; i < 4; ++i)
#pragma unroll
    for (int j = 0; j < 4; ++j) acc[i][j] = vzero;

  for (int kt = 0; kt < K / 64; ++kt) {
    const int k0 = kt * 64;
#pragma unroll
    for (int p = 0; p < 4; ++p) {
      int idx = t + p * 256;
      int row = idx >> 3, seg = idx & 7;
      gl_lds16(&A[(long)(m0 + row) * K + k0 + seg * 8], &As[idx * 8]);
      gl_lds16(&B[(long)(n0 + row) * K + k0 + seg * 8], &Bs[idx * 8]);
    }
    __syncthreads();
#pragma unroll
    for (int ks = 0; ks < 64; ks += 32) {
      bf16x8 af[4], bfg[4];
#pragma unroll
      for (int i = 0; i < 4; ++i)
        af[i] = *(const bf16x8*)&As[(wr * 64 + i * 16 + l15) * 64 + ks + quad * 8];
#pragma unroll
      for (int j = 0; j < 4; ++j)
        bfg[j] = *(const bf16x8*)&Bs[(wc * 64 + j * 16 + l15) * 64 + ks + quad * 8];
#pragma unroll
      for (int i = 0; i < 4; ++i)
#pragma unroll
        for (int j = 0; j < 4; ++j)
          acc[i][j] = __builtin_amdgcn_mfma_f32_16x16x32_bf16(af[i], bfg[j], acc[i][j], 0, 0, 0);
    }
    __syncthreads();
  }

  float cb[4];
#pragma unroll
  for (int j = 0; j < 4; ++j) cb[j] = bias[n0 + wc * 64 + j * 16 + l15];

#pragma unroll
  for (int i = 0; i < 4; ++i) {
#pragma unroll
    for (int r = 0; r < 4; ++r) {
      int row = m0 + wr * 64 + i * 16 + quad * 4 + r;
      long base = (long)row * 1024 + n0 + wc * 64;
#pragma unroll
      for (int j = 0; j < 4; ++j)
        C[base + j * 16 + l15] = acc[i][j][r] + cb[j];
    }
  }
}

// ---------------------------------------------------------------- attention (split-K)
// Slots per (b,h): 0..7 = qb=slot, chunks [0,qb], direct output. 8..23 = qb=8+((s)>>1),
// part=s&1 (part0 [0,7], part1 [8,qb]) -> unnormalized partials.
// All LDS staging via global_load_lds (K from Kb rows, V from Vtg rows). Ws stride 68.
__global__ __launch_bounds__(256) void attn_split(
    const u16* __restrict__ Qb,     // [4096][1024]
    const u16* __restrict__ Kb,     // [4096][1024]
    const u16* __restrict__ Vtg,    // [1024][4096]  V^T: row h*64+d, col b*1024+t
    const float* __restrict__ rel_bias,  // [63][16]
    u16* __restrict__ att,          // == Qb (in-place, disjoint rows)
    u16* __restrict__ Opart,        // [1024][64][64]
    float* __restrict__ Dpart) {    // [1024][64]
  constexpr int WS = 68;            // Ws row stride (u16): banks fully spread
  __shared__ __align__(16) u16 Ks[64 * 64];
  __shared__ __align__(16) u16 Vts[64 * 64];
  __shared__ __align__(16) u16 Ws[4][16 * WS];
  __shared__ float biasl[64];

  const int bx = blockIdx.x;
  const int bh = bx / 24;
  const int slot = bx - bh * 24;
  const int b = bh >> 4, h = bh & 15;

  int qb, cbeg, cend, pidx;
  bool multi;
  if (slot < 8) { qb = slot; cbeg = 0; cend = qb; multi = false; pidx = 0; }
  else {
    int s = slot - 8;
    qb = 8 + (s >> 1);
    int part = s & 1;
    multi = true;
    pidx = (bh * 8 + (qb - 8)) * 2 + part;
    if (part == 0) { cbeg = 0; cend = 7; }
    else           { cbeg = 8; cend = qb; }
  }
  const int q0 = qb * 64;

  const int t = threadIdx.x;
  const int lane = t & 63;
  const int wv = t >> 6;
  const int quad = lane >> 4;
  const int l15 = lane & 15;

  if (t < 63) biasl[t] = rel_bias[t * 16 + h];

  const long qrow = (long)(b * 1024 + q0 + wv * 16 + l15) * 1024 + h * 64;
  bf16x8 qf0 = *(const bf16x8*)&Qb[qrow + quad * 8];
  bf16x8 qf1 = *(const bf16x8*)&Qb[qrow + 32 + quad * 8];

  const f32x4 vzero = {0.f, 0.f, 0.f, 0.f};
  f32x4 acc_o[4];
#pragma unroll
  for (int j = 0; j < 4; ++j) acc_o[j] = vzero;
  f32x4 denom = vzero;
  const float scale = 0.125f;  // 64^-0.5
  const int myq = q0 + wv * 16 + quad * 4;

  for (int c = cbeg; c <= cend; ++c) {
    const int k0 = c * 64;
    if (c != cbeg) __syncthreads();
    // stage K chunk: 64 key-rows x 64 d  (16B/lane, conflict-free)
#pragma unroll
    for (int p = 0; p < 2; ++p) {
      int idx = t + p * 256;
      int row = idx >> 3, seg = idx & 7;
      gl_lds16(&Kb[(long)(b * 1024 + k0 + row) * 1024 + h * 64 + seg * 8], &Ks[idx * 8]);
    }
    // stage V^T chunk: 64 d-rows x 64 keys (16B/lane, no transpose needed)
#pragma unroll
    for (int p = 0; p < 2; ++p) {
      int idx = t + p * 256;
      int row = idx >> 3, seg = idx & 7;
      gl_lds16(&Vtg[(long)(h * 64 + row) * 4096 + b * 1024 + k0 + seg * 8], &Vts[idx * 8]);
    }
    __syncthreads();

    // S tiles + weight transform
#pragma unroll
    for (int g = 0; g < 4; ++g) {
      bf16x8 kf0 = *(const bf16x8*)&Ks[(g * 16 + l15) * 64 + quad * 8];
      bf16x8 kf1 = *(const bf16x8*)&Ks[(g * 16 + l15) * 64 + 32 + quad * 8];
      f32x4 s = vzero;
      s = __builtin_amdgcn_mfma_f32_16x16x32_bf16(qf0, kf0, s, 0, 0, 0);
      s = __builtin_amdgcn_mfma_f32_16x16x32_bf16(qf1, kf1, s, 0, 0, 0);
      const int kg = k0 + g * 16 + l15;
#pragma unroll
      for (int r = 0; r < 4; ++r) {
        int q = myq + r;
        int dd = kg - q;
        dd = dd < -31 ? -31 : (dd > 31 ? 31 : dd);
        float sv = s[r] * scale + biasl[dd + 31];
        float w = (kg <= q) ? (fmaxf(sv, 0.f) + 1e-6f) : 0.f;
        u16 wb = f2bf(w);
        denom[r] += bf2f(wb);  // accumulate exactly what PV consumes
        Ws[wv][(quad * 4 + r) * WS + g * 16 + l15] = wb;
      }
    }
    // intra-wave LDS write->read ordering (Ws[wv] is wave-private)
    asm volatile("s_waitcnt lgkmcnt(0)" ::: "memory");
    // PV: O[q,d] += W[q,k] * V[k,d]; A-frag from Ws (2x b64, stride 68), B-frag from Vts
#pragma unroll
    for (int ks = 0; ks < 64; ks += 32) {
      union { bf16x8 v8; bf16x4 v4[2]; } au;
      int wbase = l15 * WS + ks + quad * 8;
      au.v4[0] = *(const bf16x4*)&Ws[wv][wbase];
      au.v4[1] = *(const bf16x4*)&Ws[wv][wbase + 4];
#pragma unroll
      for (int j = 0; j < 4; ++j) {
        bf16x8 bvv = *(const bf16x8*)&Vts[(j * 16 + l15) * 64 + ks + quad * 8];
        acc_o[j] = __builtin_amdgcn_mfma_f32_16x16x32_bf16(au.v8, bvv, acc_o[j], 0, 0, 0);
      }
    }
  }

  // denom: sum across the 16 key-lanes of each quad
#pragma unroll
  for (int m = 1; m < 16; m <<= 1)
#pragma unroll
    for (int r = 0; r < 4; ++r) denom[r] += __shfl_xor(denom[r], m);

  if (!multi) {
    float inv[4];
#pragma unroll
    for (int r = 0; r < 4; ++r) inv[r] = 1.f / (denom[r] + 1e-6f);
#pragma unroll
    for (int j = 0; j < 4; ++j)
#pragma unroll
      for (int r = 0; r < 4; ++r) {
        int q = myq + r;
        att[(long)(b * 1024 + q) * 1024 + h * 64 + j * 16 + l15] = f2bf(acc_o[j][r] * inv[r]);
      }
  } else {
    const int qrel = wv * 16 + quad * 4;
#pragma unroll
    for (int j = 0; j < 4; ++j)
#pragma unroll
      for (int r = 0; r < 4; ++r)
        Opart[(long)pidx * 4096 + (qrel + r) * 64 + j * 16 + l15] = f2bf(acc_o[j][r]);
    if (l15 == 0) {
#pragma unroll
      for (int r = 0; r < 4; ++r) Dpart[pidx * 64 + qrel + r] = denom[r];
    }
  }
}

// ---------------------------------------------------------------- partial combine
__global__ __launch_bounds__(256) void attn_reduce(
    const u16* __restrict__ Opart, const float* __restrict__ Dpart,
    u16* __restrict__ att) {
  const int bx = blockIdx.x;
  const int bh = bx >> 3;
  const int q8 = bx & 7;
  const int b = bh >> 4, h = bh & 15;
  const int qb = 8 + q8;
  const int pidx = (bh * 8 + q8) * 2;

  const int t = threadIdx.x;
  const int row = t >> 2;
  const int dseg = t & 3;

  const float d0 = Dpart[pidx * 64 + row];
  const float d1 = Dpart[(pidx + 1) * 64 + row];
  const float inv = 1.f / (d0 + d1 + 1e-6f);

  const u16* O0 = Opart + (long)pidx * 4096 + row * 64 + dseg * 16;
  const u16* O1 = O0 + 4096;
  union { uint4 q[2]; u16 s[16]; } a, c, o;
  a.q[0] = *(const uint4*)O0;       a.q[1] = *(const uint4*)(O0 + 8);
  c.q[0] = *(const uint4*)O1;       c.q[1] = *(const uint4*)(O1 + 8);
#pragma unroll
  for (int i = 0; i < 16; ++i) o.s[i] = f2bf((bf2f(a.s[i]) + bf2f(c.s[i])) * inv);
  u16* dst = att + (long)(b * 1024 + qb * 64 + row) * 1024 + h * 64 + dseg * 16;
  *(uint4*)dst = o.q[0];
  *(uint4*)(dst + 8) = o.q[1];
}

// ---------------------------------------------------------------- launch
extern "C" void kernel_launch(void* const* d_in, const int* in_sizes, int n_in,
                              void* d_out, int out_size, void* d_ws, size_t ws_size,
                              hipStream_t stream) {
  const float* x  = (const float*)d_in[0];
  const float* Wq = (const float*)d_in[2];
  const float* bq = (const float*)d_in[3];
  const float* Wk = (const float*)d_in[4];
  const float* bk = (const float*)d_in[5];
  const float* Wv = (const float*)d_in[6];
  const float* bv = (const float*)d_in[7];
  const float* Wo = (const float*)d_in[8];
  const float* bo = (const float*)d_in[9];
  const float* rb = (const float*)d_in[10];

  char* ws = (char*)d_ws;
  u16* xb      = (u16*)(ws);
  u16* Opart   = (u16*)(ws);                 // reuses xb after QKV
  u16* wqb     = (u16*)(ws + (8l  << 20));
  float* Dpart = (float*)(ws + (8l << 20));  // reuses wqb after QKV
  u16* wkb     = (u16*)(ws + (10l << 20));
  u16* wvb     = (u16*)(ws + (12l << 20));
  u16* wob     = (u16*)(ws + (14l << 20));
  u16* Qb      = (u16*)(ws + (16l << 20));
  u16* Kb      = (u16*)d_out;
  u16* Vtg     = (u16*)((char*)d_out + (8l << 20));

  cast_all_kernel<<<8192, 256, 0, stream>>>(x, Wq, Wk, Wv, Wo, xb, wqb, wkb, wvb, wob);
  gemm_qkv<<<768, 256, 0, stream>>>(xb, wqb, wkb, wvb, bq, bk, bv, Qb, Kb, Vtg);
  attn_split<<<1536, 256, 0, stream>>>(Qb, Kb, Vtg, rb, Qb, Opart, Dpart);
  attn_reduce<<<512, 256, 0, stream>>>(Opart, Dpart, Qb);
  gemm_out<<<dim3(32, 8), 256, 0, stream>>>(Qb, wob, bo, (float*)d_out);
}

// Round 6
// 202.980 us; speedup vs baseline: 1.1310x; 1.1310x over previous
//
#include <hip/hip_runtime.h>

// AlgebraicAttention on MI355X (gfx950), round 6.
// R5 post-mortem: PV/QK LDS frag reads at row-stride 64 = 16-way bank conflicts (all
// l15 lanes same bank); epilogue did 16 LDS bias gathers + 16 scalar Ws writes per lane.
// Fixes: (1) S^T = K*Q^T (swapped MFMA operands) -> lane holds 4 consecutive-k W values
// for fixed q=l15 -> Ws spill = 1 ds_write_b64; (2) K/V^T staged via registers into
// XOR-swizzled (seg^row&7) stride-64 LDS -> b128 reads/writes at 8-phase floor;
// (3) constant-bias fast path for c<=qb-2 (clipped rel-bias == rel_bias[0][h], mask
// trivially true); (4) gemm_qkv block remap: Q/K n-group-major, V^T n-tile shared.
// ws: [0,8M) xb->Opart | [8,10M) wqb->Dpart | [10,12M) wkb | [12,14M) wvb |
//     [14,16M) wob | [16,24M) Qb (att in-place). d_out: [0,8M) Kb | [8,16M) Vtg.

typedef __attribute__((ext_vector_type(8))) __bf16 bf16x8;
typedef __attribute__((ext_vector_type(4))) __bf16 bf16x4;
typedef __attribute__((ext_vector_type(4))) float f32x4;
typedef unsigned short u16;

__device__ __forceinline__ u16 f2bf(float f) {
  unsigned u = __float_as_uint(f);
  u += 0x7FFFu + ((u >> 16) & 1u);   // round-to-nearest-even
  return (u16)(u >> 16);
}
__device__ __forceinline__ float bf2f(u16 b) {
  return __uint_as_float(((unsigned)b) << 16);
}
__device__ __forceinline__ void gl_lds16(const void* g, void* l) {
  __builtin_amdgcn_global_load_lds((__attribute__((address_space(1))) void*)g,
                                   (__attribute__((address_space(3))) void*)l,
                                   16, 0, 0);
}

// ---------------------------------------------------------------- cast kernel
__global__ __launch_bounds__(256) void cast_all_kernel(
    const float* __restrict__ x,  const float* __restrict__ wq,
    const float* __restrict__ wk, const float* __restrict__ wv,
    const float* __restrict__ wo,
    u16* __restrict__ xb, u16* __restrict__ wqb, u16* __restrict__ wkb,
    u16* __restrict__ wvb, u16* __restrict__ wob) {
  long i4 = (long)blockIdx.x * 256 + threadIdx.x;
  const float* src; u16* dst; long rel;
  if (i4 < 1048576) { src = x; dst = xb; rel = i4; }
  else {
    long j = i4 - 1048576;
    int w = (int)(j >> 18);
    rel = j & 262143;
    src = (w == 0) ? wq : (w == 1) ? wk : (w == 2) ? wv : wo;
    dst = (w == 0) ? wqb : (w == 1) ? wkb : (w == 2) ? wvb : wob;
  }
  float4 v = ((const float4*)src)[rel];
  ushort4 o;
  o.x = f2bf(v.x); o.y = f2bf(v.y); o.z = f2bf(v.z); o.w = f2bf(v.w);
  ((ushort4*)dst)[rel] = o;
}

// ---------------------------------------------------------------- fused QKV + V^T GEMM
// bx<512: Q/K. group g=bx>>5: sel=g>>3, n0=(g&7)*128; m0=(bx&31)*128 (B-tile shared
// across consecutive 32 blocks). bx>=512: V^T=Wv@x^T. rem=bx-512: n0=(rem>>3)*128,
// m0=(rem&7)*128 (xb n-tile shared across consecutive 8 blocks; Wv fully L2-hot).
__global__ __launch_bounds__(256) void gemm_qkv(
    const u16* __restrict__ xb, const u16* __restrict__ wqb,
    const u16* __restrict__ wkb, const u16* __restrict__ wvb,
    const float* __restrict__ bq, const float* __restrict__ bk,
    const float* __restrict__ bv,
    u16* __restrict__ Qb, u16* __restrict__ Kb, u16* __restrict__ Vtg) {
  constexpr int K = 1024;
  __shared__ __align__(16) u16 As[128 * 64];
  __shared__ __align__(16) u16 Bs[128 * 64];

  const int bx = blockIdx.x;
  const u16 *AT, *BT;
  const float* bias;
  u16* C;
  int m0, n0, ldc;
  bool rowbias;
  if (bx < 512) {
    int g = bx >> 5;
    int sel = g >> 3;
    n0 = (g & 7) * 128; m0 = (bx & 31) * 128;
    AT = xb; BT = sel ? wkb : wqb; bias = sel ? bk : bq;
    C = sel ? Kb : Qb; ldc = 1024; rowbias = false;
  } else {
    int rem = bx - 512;
    n0 = (rem >> 3) * 128; m0 = (rem & 7) * 128;
    AT = wvb; BT = xb; bias = bv;
    C = Vtg; ldc = 4096; rowbias = true;
  }

  const int t = threadIdx.x;
  const int lane = t & 63;
  const int wv = t >> 6;
  const int quad = lane >> 4;
  const int l15 = lane & 15;
  const int wr = wv >> 1, wc = wv & 1;

  const f32x4 vzero = {0.f, 0.f, 0.f, 0.f};
  f32x4 acc[4][4];
#pragma unroll
  for (int i = 0; i < 4; ++i)
#pragma unroll
    for (int j = 0; j < 4; ++j) acc[i][j] = vzero;

  for (int kt = 0; kt < K / 64; ++kt) {
    const int k0 = kt * 64;
#pragma unroll
    for (int p = 0; p < 4; ++p) {
      int idx = t + p * 256;
      int row = idx >> 3, seg = idx & 7;
      gl_lds16(&AT[(long)(m0 + row) * K + k0 + seg * 8], &As[idx * 8]);
      gl_lds16(&BT[(long)(n0 + row) * K + k0 + seg * 8], &Bs[idx * 8]);
    }
    __syncthreads();
#pragma unroll
    for (int ks = 0; ks < 64; ks += 32) {
      bf16x8 af[4], bfg[4];
#pragma unroll
      for (int i = 0; i < 4; ++i)
        af[i] = *(const bf16x8*)&As[(wr * 64 + i * 16 + l15) * 64 + ks + quad * 8];
#pragma unroll
      for (int j = 0; j < 4; ++j)
        bfg[j] = *(const bf16x8*)&Bs[(wc * 64 + j * 16 + l15) * 64 + ks + quad * 8];
#pragma unroll
      for (int i = 0; i < 4; ++i)
#pragma unroll
        for (int j = 0; j < 4; ++j)
          acc[i][j] = __builtin_amdgcn_mfma_f32_16x16x32_bf16(af[i], bfg[j], acc[i][j], 0, 0, 0);
    }
    __syncthreads();
  }

  float cb[4];
  if (!rowbias) {
#pragma unroll
    for (int j = 0; j < 4; ++j) cb[j] = bias[n0 + wc * 64 + j * 16 + l15];
  }

#pragma unroll
  for (int i = 0; i < 4; ++i) {
#pragma unroll
    for (int r = 0; r < 4; ++r) {
      int row = m0 + wr * 64 + i * 16 + quad * 4 + r;
      long base = (long)row * ldc + n0 + wc * 64;
      float rb_ = rowbias ? bias[row] : 0.f;
#pragma unroll
      for (int j = 0; j < 4; ++j) {
        float v = acc[i][j][r] + (rowbias ? rb_ : cb[j]);
        C[base + j * 16 + l15] = f2bf(v);
      }
    }
  }
}

// ---------------------------------------------------------------- output GEMM (fp32 out)
__global__ __launch_bounds__(256) void gemm_out(
    const u16* __restrict__ A, const u16* __restrict__ B,
    const float* __restrict__ bias, float* __restrict__ C) {
  constexpr int K = 1024;
  __shared__ __align__(16) u16 As[128 * 64];
  __shared__ __align__(16) u16 Bs[128 * 64];

  const int m0 = blockIdx.x * 128;
  const int n0 = blockIdx.y * 128;

  const int t = threadIdx.x;
  const int lane = t & 63;
  const int wv = t >> 6;
  const int quad = lane >> 4;
  const int l15 = lane & 15;
  const int wr = wv >> 1, wc = wv & 1;

  const f32x4 vzero = {0.f, 0.f, 0.f, 0.f};
  f32x4 acc[4][4];
#pragma unroll
  for (int i = 0; i < 4; ++i)
#pragma unroll
    for (int j = 0; j < 4; ++j) acc[i][j] = vzero;

  for (int kt = 0; kt < K / 64; ++kt) {
    const int k0 = kt * 64;
#pragma unroll
    for (int p = 0; p < 4; ++p) {
      int idx = t + p * 256;
      int row = idx >> 3, seg = idx & 7;
      gl_lds16(&A[(long)(m0 + row) * K + k0 + seg * 8], &As[idx * 8]);
      gl_lds16(&B[(long)(n0 + row) * K + k0 + seg * 8], &Bs[idx * 8]);
    }
    __syncthreads();
#pragma unroll
    for (int ks = 0; ks < 64; ks += 32) {
      bf16x8 af[4], bfg[4];
#pragma unroll
      for (int i = 0; i < 4; ++i)
        af[i] = *(const bf16x8*)&As[(wr * 64 + i * 16 + l15) * 64 + ks + quad * 8];
#pragma unroll
      for (int j = 0; j < 4; ++j)
        bfg[j] = *(const bf16x8*)&Bs[(wc * 64 + j * 16 + l15) * 64 + ks + quad * 8];
#pragma unroll
      for (int i = 0; i < 4; ++i)
#pragma unroll
        for (int j = 0; j < 4; ++j)
          acc[i][j] = __builtin_amdgcn_mfma_f32_16x16x32_bf16(af[i], bfg[j], acc[i][j], 0, 0, 0);
    }
    __syncthreads();
  }

  float cb[4];
#pragma unroll
  for (int j = 0; j < 4; ++j) cb[j] = bias[n0 + wc * 64 + j * 16 + l15];

#pragma unroll
  for (int i = 0; i < 4; ++i) {
#pragma unroll
    for (int r = 0; r < 4; ++r) {
      int row = m0 + wr * 64 + i * 16 + quad * 4 + r;
      long base = (long)row * 1024 + n0 + wc * 64;
#pragma unroll
      for (int j = 0; j < 4; ++j)
        C[base + j * 16 + l15] = acc[i][j][r] + cb[j];
    }
  }
}

// ---------------------------------------------------------------- attention (split-K, S^T)
// Slots per (b,h): 0..7 = qb=slot, chunks [0,qb], direct out. 8..23 = qb=8+(s>>1),
// part s&1 (part0 [0,7], part1 [8,qb]) -> partials. S^T = mfma(K-frag, Q-frag):
// lane holds S^T[key=g*16+quad*4+r][q=l15] -> Ws[q][k] spill = 1 ds_write_b64.
// K/V^T in XOR-swizzled LDS (addr row*64 + (seg^(row&7))*8): b128 R/W at phase floor.
__global__ __launch_bounds__(256) void attn_split(
    const u16* __restrict__ Qb,     // [4096][1024]
    const u16* __restrict__ Kb,     // [4096][1024]
    const u16* __restrict__ Vtg,    // [1024][4096] V^T
    const float* __restrict__ rel_bias,  // [63][16]
    u16* __restrict__ att,          // == Qb (in-place, disjoint rows)
    u16* __restrict__ Opart,        // [1024][64][64]
    float* __restrict__ Dpart) {    // [1024][64]
  constexpr int WS = 68;
  __shared__ __align__(16) u16 Kt[64 * 64];
  __shared__ __align__(16) u16 Vt[64 * 64];
  __shared__ __align__(16) u16 Ws[4][16 * WS];
  __shared__ float biasl[64];

  const int bx = blockIdx.x;
  const int bh = bx / 24;
  const int slot = bx - bh * 24;
  const int b = bh >> 4, h = bh & 15;

  int qb, cbeg, cend, pidx;
  bool multi;
  if (slot < 8) { qb = slot; cbeg = 0; cend = qb; multi = false; pidx = 0; }
  else {
    int s = slot - 8;
    qb = 8 + (s >> 1);
    int part = s & 1;
    multi = true;
    pidx = (bh * 8 + (qb - 8)) * 2 + part;
    if (part == 0) { cbeg = 0; cend = 7; }
    else           { cbeg = 8; cend = qb; }
  }
  const int q0 = qb * 64;

  const int t = threadIdx.x;
  const int lane = t & 63;
  const int wv = t >> 6;
  const int quad = lane >> 4;
  const int l15 = lane & 15;

  if (t < 63) biasl[t] = rel_bias[t * 16 + h];
  const float b0c = rel_bias[h];           // clipped bias for dd <= -31

  // Q fragments: lane holds Q[q=l15][d=quad*8+j] (+32) — valid as both A and B operand
  const long qrow = (long)(b * 1024 + q0 + wv * 16 + l15) * 1024 + h * 64;
  bf16x8 qf0 = *(const bf16x8*)&Qb[qrow + quad * 8];
  bf16x8 qf1 = *(const bf16x8*)&Qb[qrow + 32 + quad * 8];

  const f32x4 vzero = {0.f, 0.f, 0.f, 0.f};
  f32x4 acc_o[4];
#pragma unroll
  for (int j = 0; j < 4; ++j) acc_o[j] = vzero;
  float denom = 0.f;
  const float scale = 0.125f;  // 64^-0.5
  const int ql = q0 + wv * 16 + l15;       // this lane's q (S^T layout)
  const int sw0 = (quad ^ (l15 & 7)) * 8;        // swizzled seg for d/key in [quad*8, +8)
  const int sw1 = ((4 + quad) ^ (l15 & 7)) * 8;  // ... in [32+quad*8, +8)

  for (int c = cbeg; c <= cend; ++c) {
    const int k0 = c * 64;
    if (c != cbeg) __syncthreads();
    // stage K [key][d] and V^T [d][key] via registers into swizzled LDS
#pragma unroll
    for (int p = 0; p < 2; ++p) {
      int idx = t + p * 256;
      int row = idx >> 3, seg = idx & 7;
      int sw = row * 64 + ((seg ^ (row & 7)) * 8);
      uint4 kv = *(const uint4*)&Kb[(long)(b * 1024 + k0 + row) * 1024 + h * 64 + seg * 8];
      uint4 vv = *(const uint4*)&Vtg[(long)(h * 64 + row) * 4096 + b * 1024 + k0 + seg * 8];
      *(uint4*)&Kt[sw] = kv;
      *(uint4*)&Vt[sw] = vv;
    }
    __syncthreads();

    const bool fast = (c <= qb - 2);
    // S^T tiles: per g, lane gets S^T[key=g*16+quad*4+r][q=l15]
#pragma unroll
    for (int g = 0; g < 4; ++g) {
      const u16* kr = &Kt[(g * 16 + l15) * 64];
      bf16x8 kf0 = *(const bf16x8*)&kr[sw0];
      bf16x8 kf1 = *(const bf16x8*)&kr[sw1];
      f32x4 sT = vzero;
      sT = __builtin_amdgcn_mfma_f32_16x16x32_bf16(kf0, qf0, sT, 0, 0, 0);
      sT = __builtin_amdgcn_mfma_f32_16x16x32_bf16(kf1, qf1, sT, 0, 0, 0);
      const int kgb = k0 + g * 16 + quad * 4;
      ushort4 wpk;
      if (fast) {
#pragma unroll
        for (int r = 0; r < 4; ++r) {
          float w = fmaxf(sT[r] * scale + b0c, 0.f) + 1e-6f;
          u16 wb = f2bf(w);
          denom += bf2f(wb);
          ((u16*)&wpk)[r] = wb;
        }
      } else {
#pragma unroll
        for (int r = 0; r < 4; ++r) {
          int kg = kgb + r;
          int dd = kg - ql;
          dd = dd < -31 ? -31 : (dd > 31 ? 31 : dd);
          float sv = sT[r] * scale + biasl[dd + 31];
          float w = (kg <= ql) ? (fmaxf(sv, 0.f) + 1e-6f) : 0.f;
          u16 wb = f2bf(w);
          denom += bf2f(wb);
          ((u16*)&wpk)[r] = wb;
        }
      }
      *(ushort4*)&Ws[wv][l15 * WS + g * 16 + quad * 4] = wpk;
    }
    asm volatile("s_waitcnt lgkmcnt(0)" ::: "memory");
    // PV: O[q,d] += W[q,k] V[k,d]. A=Ws[q=l15][k], B=V^T from swizzled Vt.
#pragma unroll
    for (int ks = 0; ks < 64; ks += 32) {
      union { bf16x8 v8; bf16x4 v4[2]; } au;
      int wbase = l15 * WS + ks + quad * 8;
      au.v4[0] = *(const bf16x4*)&Ws[wv][wbase];
      au.v4[1] = *(const bf16x4*)&Ws[wv][wbase + 4];
      const int sv = ks ? sw1 : sw0;
#pragma unroll
      for (int j = 0; j < 4; ++j) {
        bf16x8 bvv = *(const bf16x8*)&Vt[(j * 16 + l15) * 64 + sv];
        acc_o[j] = __builtin_amdgcn_mfma_f32_16x16x32_bf16(au.v8, bvv, acc_o[j], 0, 0, 0);
      }
    }
  }

  // denom for q=l15: reduce across the 4 quads
  denom += __shfl_xor(denom, 16);
  denom += __shfl_xor(denom, 32);

  if (!multi) {
    float invm = 1.f / (denom + 1e-6f);
    float inv[4];
#pragma unroll
    for (int r = 0; r < 4; ++r) inv[r] = __shfl(invm, quad * 4 + r);  // q-row quad*4+r
#pragma unroll
    for (int j = 0; j < 4; ++j)
#pragma unroll
      for (int r = 0; r < 4; ++r) {
        int q = q0 + wv * 16 + quad * 4 + r;
        att[(long)(b * 1024 + q) * 1024 + h * 64 + j * 16 + l15] = f2bf(acc_o[j][r] * inv[r]);
      }
  } else {
    const int qrel = wv * 16 + quad * 4;
#pragma unroll
    for (int j = 0; j < 4; ++j)
#pragma unroll
      for (int r = 0; r < 4; ++r)
        Opart[(long)pidx * 4096 + (qrel + r) * 64 + j * 16 + l15] = f2bf(acc_o[j][r]);
    if (quad == 0) Dpart[pidx * 64 + wv * 16 + l15] = denom;
  }
}

// ---------------------------------------------------------------- partial combine
__global__ __launch_bounds__(256) void attn_reduce(
    const u16* __restrict__ Opart, const float* __restrict__ Dpart,
    u16* __restrict__ att) {
  const int bx = blockIdx.x;
  const int bh = bx >> 3;
  const int q8 = bx & 7;
  const int b = bh >> 4, h = bh & 15;
  const int qb = 8 + q8;
  const int pidx = (bh * 8 + q8) * 2;

  const int t = threadIdx.x;
  const int row = t >> 2;
  const int dseg = t & 3;

  const float d0 = Dpart[pidx * 64 + row];
  const float d1 = Dpart[(pidx + 1) * 64 + row];
  const float inv = 1.f / (d0 + d1 + 1e-6f);

  const u16* O0 = Opart + (long)pidx * 4096 + row * 64 + dseg * 16;
  const u16* O1 = O0 + 4096;
  union { uint4 q[2]; u16 s[16]; } a, c, o;
  a.q[0] = *(const uint4*)O0;       a.q[1] = *(const uint4*)(O0 + 8);
  c.q[0] = *(const uint4*)O1;       c.q[1] = *(const uint4*)(O1 + 8);
#pragma unroll
  for (int i = 0; i < 16; ++i) o.s[i] = f2bf((bf2f(a.s[i]) + bf2f(c.s[i])) * inv);
  u16* dst = att + (long)(b * 1024 + qb * 64 + row) * 1024 + h * 64 + dseg * 16;
  *(uint4*)dst = o.q[0];
  *(uint4*)(dst + 8) = o.q[1];
}

// ---------------------------------------------------------------- launch
extern "C" void kernel_launch(void* const* d_in, const int* in_sizes, int n_in,
                              void* d_out, int out_size, void* d_ws, size_t ws_size,
                              hipStream_t stream) {
  const float* x  = (const float*)d_in[0];
  const float* Wq = (const float*)d_in[2];
  const float* bq = (const float*)d_in[3];
  const float* Wk = (const float*)d_in[4];
  const float* bk = (const float*)d_in[5];
  const float* Wv = (const float*)d_in[6];
  const float* bv = (const float*)d_in[7];
  const float* Wo = (const float*)d_in[8];
  const float* bo = (const float*)d_in[9];
  const float* rb = (const float*)d_in[10];

  char* ws = (char*)d_ws;
  u16* xb      = (u16*)(ws);
  u16* Opart   = (u16*)(ws);                 // reuses xb after QKV
  u16* wqb     = (u16*)(ws + (8l  << 20));
  float* Dpart = (float*)(ws + (8l << 20));  // reuses wqb after QKV
  u16* wkb     = (u16*)(ws + (10l << 20));
  u16* wvb     = (u16*)(ws + (12l << 20));
  u16* wob     = (u16*)(ws + (14l << 20));
  u16* Qb      = (u16*)(ws + (16l << 20));
  u16* Kb      = (u16*)d_out;
  u16* Vtg     = (u16*)((char*)d_out + (8l << 20));

  cast_all_kernel<<<8192, 256, 0, stream>>>(x, Wq, Wk, Wv, Wo, xb, wqb, wkb, wvb, wob);
  gemm_qkv<<<768, 256, 0, stream>>>(xb, wqb, wkb, wvb, bq, bk, bv, Qb, Kb, Vtg);
  attn_split<<<1536, 256, 0, stream>>>(Qb, Kb, Vtg, rb, Qb, Opart, Dpart);
  attn_reduce<<<512, 256, 0, stream>>>(Opart, Dpart, Qb);
  gemm_out<<<dim3(32, 8), 256, 0, stream>>>(Qb, wob, bo, (float*)d_out);
}